// Round 1
// baseline (211.213 us; speedup 1.0000x reference)
//
#include <hip/hip_runtime.h>
#include <hip/hip_bf16.h>

#define NB 8
#define CC 256
#define CP 32
#define NN 4096

typedef __attribute__((ext_vector_type(8))) short short8;
typedef __attribute__((ext_vector_type(4))) float floatx4;
typedef __attribute__((ext_vector_type(4))) int intx4;

static __device__ __forceinline__ ushort bf16r(float f) {
    __hip_bfloat16 h = __float2bfloat16(f);
    return *reinterpret_cast<ushort*>(&h);
}
static __device__ __forceinline__ float bf2f(ushort u) {
    union { unsigned int i; float f; } x;
    x.i = ((unsigned int)u) << 16;
    return x.f;
}
static __device__ __forceinline__ short8 load_frag(const ushort* p) {
    intx4 v = *reinterpret_cast<const intx4*>(p);
    return *reinterpret_cast<short8*>(&v);
}

// ---------------- Kernel 0: convert Wq/Wk/Wv to bf16, packed [96][256] ----------------
__global__ void prep_w(const float* __restrict__ Wq, const float* __restrict__ Wk,
                       const float* __restrict__ Wv, ushort* __restrict__ W96) {
    int r = blockIdx.x, c = threadIdx.x;
    const float* src = (r < 32) ? (Wq + r * CC) : ((r < 64) ? (Wk + (r - 32) * CC) : (Wv + (r - 64) * CC));
    W96[r * CC + c] = bf16r(src[c]);
}

// ---------------- Kernel 1: projection x -> Qt, Kt, Vt  (all [b][n][32] bf16) ----------------
// D[o][n] = sum_c W96[o][c] * x[b][c][n]; A = W96 rows (contig k=c), B = x columns (gathered k=c)
__global__ __launch_bounds__(256) void proj_kernel(
    const float* __restrict__ x, const ushort* __restrict__ W96,
    const float* __restrict__ bq, const float* __restrict__ bk, const float* __restrict__ bv,
    ushort* __restrict__ Qt, ushort* __restrict__ Kt, ushort* __restrict__ Vt) {
    int b = blockIdx.x >> 6;
    int nt = blockIdx.x & 63;
    int w = threadIdx.x >> 6, lane = threadIdx.x & 63;
    int l15 = lane & 15, q = lane >> 4;
    int n = nt * 64 + w * 16 + l15;
    const float* xb = x + (size_t)b * CC * NN + n;  // x[b][c][n] = xb[c*NN]

    floatx4 acc[6];
#pragma unroll
    for (int t = 0; t < 6; t++) acc[t] = (floatx4){0.f, 0.f, 0.f, 0.f};

#pragma unroll
    for (int ks = 0; ks < 8; ks++) {
        int cbase = ks * 32 + q * 8;
        float xv[8];
#pragma unroll
        for (int jj = 0; jj < 8; jj++) xv[jj] = xb[(size_t)(cbase + jj) * NN];
        short8 bfrag;
#pragma unroll
        for (int jj = 0; jj < 8; jj++) bfrag[jj] = (short)bf16r(xv[jj]);
#pragma unroll
        for (int ot = 0; ot < 6; ot++) {
            short8 afrag = load_frag(&W96[(size_t)(ot * 16 + l15) * CC + ks * 32 + q * 8]);
            acc[ot] = __builtin_amdgcn_mfma_f32_16x16x32_bf16(afrag, bfrag, acc[ot], 0, 0, 0);
        }
    }
    // epilogue: D rows o = ot*16 + q*4 + r, col n
#pragma unroll
    for (int ot = 0; ot < 6; ot++) {
        const float* bias = (ot < 2) ? bq : ((ot < 4) ? bk : bv);
        ushort* dst = (ot < 2) ? Qt : ((ot < 4) ? Kt : Vt);
        int o0 = (ot & 1) * 16 + q * 4;
        float4 b4 = *reinterpret_cast<const float4*>(bias + o0);
        ushort4 pk;
        pk.x = bf16r(acc[ot][0] + b4.x);
        pk.y = bf16r(acc[ot][1] + b4.y);
        pk.z = bf16r(acc[ot][2] + b4.z);
        pk.w = bf16r(acc[ot][3] + b4.w);
        *reinterpret_cast<ushort4*>(&dst[((size_t)b * NN + n) * CP + o0]) = pk;
    }
}

// ---------------- Kernel 2: pass A — F[b][j] = 1 / sum_m exp(q_j . k_m) ----------------
__global__ __launch_bounds__(256) void passA_kernel(
    const ushort* __restrict__ Qt, const ushort* __restrict__ Kt, float* __restrict__ F) {
    __shared__ ushort kst[256 * CP];  // 16 KB: K-chunk [256 m][32 o]
    int b = blockIdx.x >> 6, jt = blockIdx.x & 63;
    int w = threadIdx.x >> 6, lane = threadIdx.x & 63;
    int l15 = lane & 15, q = lane >> 4;
    int j = jt * 64 + w * 16 + l15;

    short8 af = load_frag(&Qt[((size_t)b * NN + j) * CP + q * 8]);
    floatx4 lacc = (floatx4){0.f, 0.f, 0.f, 0.f};

    for (int m0 = 0; m0 < NN; m0 += 256) {
        __syncthreads();
        {
            const intx4* src = reinterpret_cast<const intx4*>(&Kt[((size_t)b * NN + m0) * CP]);
            intx4* dst = reinterpret_cast<intx4*>(kst);
#pragma unroll
            for (int s = 0; s < 4; s++) dst[threadIdx.x + 256 * s] = src[threadIdx.x + 256 * s];
        }
        __syncthreads();
#pragma unroll
        for (int ms = 0; ms < 16; ms++) {
            short8 bf = load_frag(&kst[(ms * 16 + l15) * CP + q * 8]);
            floatx4 z = (floatx4){0.f, 0.f, 0.f, 0.f};
            floatx4 s = __builtin_amdgcn_mfma_f32_16x16x32_bf16(af, bf, z, 0, 0, 0);
            lacc[0] += __expf(s[0]);
            lacc[1] += __expf(s[1]);
            lacc[2] += __expf(s[2]);
            lacc[3] += __expf(s[3]);
        }
    }
    // reduce over the 16 lanes of each quad-group (cols m of the last tiles)
#pragma unroll
    for (int d = 1; d < 16; d <<= 1) {
        lacc[0] += __shfl_xor(lacc[0], d, 64);
        lacc[1] += __shfl_xor(lacc[1], d, 64);
        lacc[2] += __shfl_xor(lacc[2], d, 64);
        lacc[3] += __shfl_xor(lacc[3], d, 64);
    }
    if (l15 == 0) {
        float4 f4;
        f4.x = 1.0f / lacc[0];
        f4.y = 1.0f / lacc[1];
        f4.z = 1.0f / lacc[2];
        f4.w = 1.0f / lacc[3];
        *reinterpret_cast<float4*>(&F[(size_t)b * NN + jt * 64 + w * 16 + q * 4]) = f4;
    }
}

// ---------------- Kernel 3: fold F into V, transpose -> Vp[b][32][n] bf16 ----------------
__global__ __launch_bounds__(256) void fold_kernel(
    const ushort* __restrict__ Vt, const float* __restrict__ F, ushort* __restrict__ Vp) {
    __shared__ ushort tile[32][264];
    int b = blockIdx.x >> 4, nt = blockIdx.x & 15;
    int t = threadIdx.x;
    int n = nt * 256 + t;
    float f = F[(size_t)b * NN + n];
    const ushort* src = &Vt[((size_t)b * NN + n) * CP];
#pragma unroll
    for (int c8 = 0; c8 < 4; c8++) {
        intx4 raw = *reinterpret_cast<const intx4*>(src + c8 * 8);
        const ushort* us = reinterpret_cast<const ushort*>(&raw);
#pragma unroll
        for (int e = 0; e < 8; e++) {
            tile[c8 * 8 + e][t] = bf16r(bf2f(us[e]) * f);
        }
    }
    __syncthreads();
#pragma unroll
    for (int c = 0; c < 32; c++) {
        Vp[((size_t)b * CP + c) * NN + nt * 256 + t] = tile[c][t];
    }
}

// ---------------- Kernel 4: pass B — out[c,i] = sum_j exp(S[j,i]) * v'[c,j]; fused back-proj + residual ----------------
__global__ __launch_bounds__(256) void passB_kernel(
    const ushort* __restrict__ Qt, const ushort* __restrict__ Kt, const ushort* __restrict__ Vp,
    const float* __restrict__ x, const float* __restrict__ Wb, const float* __restrict__ bb,
    float* __restrict__ out) {
    __shared__ ushort qst[256 * CP];      // 16 KB : Q-chunk [256 j][32 o]
    __shared__ ushort vst[32 * 264];      // 16.5 KB : V'-chunk [32 c][256 j] (stride 264)
    __shared__ ushort wt[2 * 4 * 16 * 40];  // 10 KB : per-wave W tile, double-buffered
    __shared__ float olds[32][68];        // 8.7 KB : out tile for epilogue

    int b = blockIdx.x >> 6, it = blockIdx.x & 63;
    int w = threadIdx.x >> 6, lane = threadIdx.x & 63;
    int l15 = lane & 15, q = lane >> 4;
    int i = it * 64 + w * 16 + l15;

    short8 kf = load_frag(&Kt[((size_t)b * NN + i) * CP + q * 8]);
    floatx4 acc0 = (floatx4){0.f, 0.f, 0.f, 0.f};
    floatx4 acc1 = (floatx4){0.f, 0.f, 0.f, 0.f};

    for (int j0 = 0; j0 < NN; j0 += 256) {
        __syncthreads();
        {
            const intx4* qsrc = reinterpret_cast<const intx4*>(&Qt[((size_t)b * NN + j0) * CP]);
            intx4* qdst = reinterpret_cast<intx4*>(qst);
#pragma unroll
            for (int s = 0; s < 4; s++) qdst[threadIdx.x + 256 * s] = qsrc[threadIdx.x + 256 * s];
            int r = threadIdx.x >> 3, ci = threadIdx.x & 7;
            const intx4* vsrc = reinterpret_cast<const intx4*>(&Vp[((size_t)b * CP + r) * NN + j0]);
            intx4* vdst = reinterpret_cast<intx4*>(&vst[r * 264]);
#pragma unroll
            for (int s = 0; s < 4; s++) vdst[ci + 8 * s] = vsrc[ci + 8 * s];
        }
        __syncthreads();
#pragma unroll
        for (int js = 0; js < 8; js++) {
            int jl = js * 32;
            short8 a0 = load_frag(&qst[(jl + l15) * CP + q * 8]);
            short8 a1 = load_frag(&qst[(jl + 16 + l15) * CP + q * 8]);
            floatx4 z = (floatx4){0.f, 0.f, 0.f, 0.f};
            floatx4 s0 = __builtin_amdgcn_mfma_f32_16x16x32_bf16(a0, kf, z, 0, 0, 0);
            floatx4 s1 = __builtin_amdgcn_mfma_f32_16x16x32_bf16(a1, kf, z, 0, 0, 0);
            ushort4 p0, p1;
            p0.x = bf16r(__expf(s0[0]));
            p0.y = bf16r(__expf(s0[1]));
            p0.z = bf16r(__expf(s0[2]));
            p0.w = bf16r(__expf(s0[3]));
            p1.x = bf16r(__expf(s1[0]));
            p1.y = bf16r(__expf(s1[1]));
            p1.z = bf16r(__expf(s1[2]));
            p1.w = bf16r(__expf(s1[3]));
            ushort* wr = &wt[((js & 1) * 64 + w * 16 + l15) * 40];
            *reinterpret_cast<ushort4*>(&wr[q * 4]) = p0;       // j_local = q*4+r  (rows 0..15)
            *reinterpret_cast<ushort4*>(&wr[16 + q * 4]) = p1;  // j_local = 16+q*4+r
            short8 wf = load_frag(&wr[q * 8]);                  // B2: k=j_local = q*8+jj
            short8 va0 = load_frag(&vst[l15 * 264 + jl + q * 8]);
            short8 va1 = load_frag(&vst[(16 + l15) * 264 + jl + q * 8]);
            acc0 = __builtin_amdgcn_mfma_f32_16x16x32_bf16(va0, wf, acc0, 0, 0, 0);
            acc1 = __builtin_amdgcn_mfma_f32_16x16x32_bf16(va1, wf, acc1, 0, 0, 0);
        }
    }

    // ---- epilogue: stash out tile [32 c][64 i] in LDS, then back-projection + bias + residual ----
    __syncthreads();
#pragma unroll
    for (int r = 0; r < 4; r++) {
        olds[q * 4 + r][w * 16 + l15] = acc0[r];
        olds[16 + q * 4 + r][w * 16 + l15] = acc1[r];
    }
    __syncthreads();

    int t = threadIdx.x;
    int i4 = (t & 15) * 4;
    int cb = t >> 4;  // 0..15
    float4 accv[16];
#pragma unroll
    for (int cc = 0; cc < 16; cc++) {
        float bbv = bb[cb + 16 * cc];
        accv[cc].x = bbv; accv[cc].y = bbv; accv[cc].z = bbv; accv[cc].w = bbv;
    }
#pragma unroll 4
    for (int o = 0; o < 32; o++) {
        float4 ovv = *reinterpret_cast<const float4*>(&olds[o][i4]);
#pragma unroll
        for (int cc = 0; cc < 16; cc++) {
            float wv = Wb[(size_t)(cb + 16 * cc) * CP + o];
            accv[cc].x += wv * ovv.x;
            accv[cc].y += wv * ovv.y;
            accv[cc].z += wv * ovv.z;
            accv[cc].w += wv * ovv.w;
        }
    }
    size_t xbase = (size_t)b * CC * NN + (size_t)it * 64 + i4;
#pragma unroll
    for (int cc = 0; cc < 16; cc++) {
        int cout = cb + 16 * cc;
        float4 xv = *reinterpret_cast<const float4*>(&x[xbase + (size_t)cout * NN]);
        float4 res;
        res.x = accv[cc].x + xv.x;
        res.y = accv[cc].y + xv.y;
        res.z = accv[cc].z + xv.z;
        res.w = accv[cc].w + xv.w;
        *reinterpret_cast<float4*>(&out[xbase + (size_t)cout * NN]) = res;
    }
}

extern "C" void kernel_launch(void* const* d_in, const int* in_sizes, int n_in,
                              void* d_out, int out_size, void* d_ws, size_t ws_size,
                              hipStream_t stream) {
    const float* x  = (const float*)d_in[0];
    const float* Wq = (const float*)d_in[1];
    const float* bq = (const float*)d_in[2];
    const float* Wk = (const float*)d_in[3];
    const float* bk = (const float*)d_in[4];
    const float* Wv = (const float*)d_in[5];
    const float* bv = (const float*)d_in[6];
    const float* Wb = (const float*)d_in[7];
    const float* bb = (const float*)d_in[8];
    float* out = (float*)d_out;

    char* ws = (char*)d_ws;
    ushort* Qt  = (ushort*)(ws);                                  // 2 MB
    ushort* Kt  = (ushort*)(ws + (2u << 20));                     // 2 MB
    ushort* Vt  = (ushort*)(ws + (4u << 20));                     // 2 MB
    ushort* Vp  = (ushort*)(ws + (6u << 20));                     // 2 MB
    float*  F   = (float*) (ws + (8u << 20));                     // 128 KB
    ushort* W96 = (ushort*)(ws + (8u << 20) + (1u << 18));        // 48 KB

    prep_w<<<96, 256, 0, stream>>>(Wq, Wk, Wv, W96);
    proj_kernel<<<512, 256, 0, stream>>>(x, W96, bq, bk, bv, Qt, Kt, Vt);
    passA_kernel<<<512, 256, 0, stream>>>(Qt, Kt, F);
    fold_kernel<<<128, 256, 0, stream>>>(Vt, F, Vp);
    passB_kernel<<<512, 256, 0, stream>>>(Qt, Kt, Vp, x, Wb, bb, out);
}

// Round 2
// 202.763 us; speedup vs baseline: 1.0417x; 1.0417x over previous
//
#include <hip/hip_runtime.h>
#include <hip/hip_bf16.h>

#define NB 8
#define CC 256
#define CP 32
#define NN 4096

typedef __attribute__((ext_vector_type(8))) short short8;
typedef __attribute__((ext_vector_type(4))) float floatx4;
typedef __attribute__((ext_vector_type(4))) int intx4;

static __device__ __forceinline__ ushort bf16r(float f) {
    __hip_bfloat16 h = __float2bfloat16(f);
    return *reinterpret_cast<ushort*>(&h);
}
static __device__ __forceinline__ float bf2f(ushort u) {
    union { unsigned int i; float f; } x;
    x.i = ((unsigned int)u) << 16;
    return x.f;
}
static __device__ __forceinline__ short8 load_frag(const ushort* p) {
    intx4 v = *reinterpret_cast<const intx4*>(p);
    return *reinterpret_cast<short8*>(&v);
}
// pack two f32 -> bf16x2 with round-to-nearest (half-up), cheap (2 add + shift + and + or)
static __device__ __forceinline__ unsigned int pk2(float a, float b) {
    unsigned int ua = __float_as_uint(a) + 0x8000u;
    unsigned int ub = __float_as_uint(b) + 0x8000u;
    return (ua >> 16) | (ub & 0xFFFF0000u);
}

// ---------------- Kernel 0: convert Wq/Wk/Wv to bf16, packed [96][256] ----------------
__global__ void prep_w(const float* __restrict__ Wq, const float* __restrict__ Wk,
                       const float* __restrict__ Wv, ushort* __restrict__ W96) {
    int r = blockIdx.x, c = threadIdx.x;
    const float* src = (r < 32) ? (Wq + r * CC) : ((r < 64) ? (Wk + (r - 32) * CC) : (Wv + (r - 64) * CC));
    W96[r * CC + c] = bf16r(src[c]);
}

// ---------------- Kernel 1: projection x -> Qt, Kt, Vt  (all [b][n][32] bf16) ----------------
__global__ __launch_bounds__(256) void proj_kernel(
    const float* __restrict__ x, const ushort* __restrict__ W96,
    const float* __restrict__ bq, const float* __restrict__ bk, const float* __restrict__ bv,
    ushort* __restrict__ Qt, ushort* __restrict__ Kt, ushort* __restrict__ Vt) {
    int b = blockIdx.x >> 6;
    int nt = blockIdx.x & 63;
    int w = threadIdx.x >> 6, lane = threadIdx.x & 63;
    int l15 = lane & 15, q = lane >> 4;
    int n = nt * 64 + w * 16 + l15;
    const float* xb = x + (size_t)b * CC * NN + n;

    floatx4 acc[6];
#pragma unroll
    for (int t = 0; t < 6; t++) acc[t] = (floatx4){0.f, 0.f, 0.f, 0.f};

#pragma unroll
    for (int ks = 0; ks < 8; ks++) {
        int cbase = ks * 32 + q * 8;
        float xv[8];
#pragma unroll
        for (int jj = 0; jj < 8; jj++) xv[jj] = xb[(size_t)(cbase + jj) * NN];
        short8 bfrag;
#pragma unroll
        for (int jj = 0; jj < 8; jj++) bfrag[jj] = (short)bf16r(xv[jj]);
#pragma unroll
        for (int ot = 0; ot < 6; ot++) {
            short8 afrag = load_frag(&W96[(size_t)(ot * 16 + l15) * CC + ks * 32 + q * 8]);
            acc[ot] = __builtin_amdgcn_mfma_f32_16x16x32_bf16(afrag, bfrag, acc[ot], 0, 0, 0);
        }
    }
#pragma unroll
    for (int ot = 0; ot < 6; ot++) {
        const float* bias = (ot < 2) ? bq : ((ot < 4) ? bk : bv);
        ushort* dst = (ot < 2) ? Qt : ((ot < 4) ? Kt : Vt);
        int o0 = (ot & 1) * 16 + q * 4;
        float4 b4 = *reinterpret_cast<const float4*>(bias + o0);
        ushort4 pk;
        pk.x = bf16r(acc[ot][0] + b4.x);
        pk.y = bf16r(acc[ot][1] + b4.y);
        pk.z = bf16r(acc[ot][2] + b4.z);
        pk.w = bf16r(acc[ot][3] + b4.w);
        *reinterpret_cast<ushort4*>(&dst[((size_t)b * NN + n) * CP + o0]) = pk;
    }
}

// ---------------- Kernel 2: pass A — partial row sums of exp(S) over m-quarters ----------------
// grid 2048: blockIdx = ((b*64 + jt)*4 + mq). Fp[mq][b][j] partial sums.
__global__ __launch_bounds__(256) void passA_kernel(
    const ushort* __restrict__ Qt, const ushort* __restrict__ Kt, float* __restrict__ Fp) {
    __shared__ ushort kst[256 * CP];  // 16 KB
    int bid = blockIdx.x;
    int mq = bid & 3;
    int jt = (bid >> 2) & 63;
    int b = bid >> 8;
    int w = threadIdx.x >> 6, lane = threadIdx.x & 63;
    int l15 = lane & 15, q = lane >> 4;
    int j = jt * 64 + w * 16 + l15;

    short8 af = load_frag(&Qt[((size_t)b * NN + j) * CP + q * 8]);
    floatx4 lacc = (floatx4){0.f, 0.f, 0.f, 0.f};

    for (int mc = 0; mc < 4; mc++) {
        int m0 = mq * 1024 + mc * 256;
        __syncthreads();
        {
            const intx4* src = reinterpret_cast<const intx4*>(&Kt[((size_t)b * NN + m0) * CP]);
            intx4* dst = reinterpret_cast<intx4*>(kst);
#pragma unroll
            for (int s = 0; s < 4; s++) dst[threadIdx.x + 256 * s] = src[threadIdx.x + 256 * s];
        }
        __syncthreads();
#pragma unroll
        for (int ms = 0; ms < 16; ms++) {
            short8 bf = load_frag(&kst[(ms * 16 + l15) * CP + q * 8]);
            floatx4 z = (floatx4){0.f, 0.f, 0.f, 0.f};
            floatx4 s = __builtin_amdgcn_mfma_f32_16x16x32_bf16(af, bf, z, 0, 0, 0);
            lacc[0] += __expf(s[0]);
            lacc[1] += __expf(s[1]);
            lacc[2] += __expf(s[2]);
            lacc[3] += __expf(s[3]);
        }
    }
#pragma unroll
    for (int d = 1; d < 16; d <<= 1) {
        lacc[0] += __shfl_xor(lacc[0], d, 64);
        lacc[1] += __shfl_xor(lacc[1], d, 64);
        lacc[2] += __shfl_xor(lacc[2], d, 64);
        lacc[3] += __shfl_xor(lacc[3], d, 64);
    }
    if (l15 == 0) {
        float4 f4;
        f4.x = lacc[0];
        f4.y = lacc[1];
        f4.z = lacc[2];
        f4.w = lacc[3];
        *reinterpret_cast<float4*>(&Fp[((size_t)mq * NB + b) * NN + jt * 64 + w * 16 + q * 4]) = f4;
    }
}

// ---------------- Kernel 3: combine Fp, fold into V, transpose -> Vp[b][32][n] bf16 ----------------
__global__ __launch_bounds__(256) void fold_kernel(
    const ushort* __restrict__ Vt, const float* __restrict__ Fp, ushort* __restrict__ Vp) {
    __shared__ ushort tile[32][264];
    const size_t PL = (size_t)NB * NN;
    int b = blockIdx.x >> 4, nt = blockIdx.x & 15;
    int t = threadIdx.x;
    int n = nt * 256 + t;
    size_t bn = (size_t)b * NN + n;
    float f = 1.0f / (Fp[bn] + Fp[PL + bn] + Fp[2 * PL + bn] + Fp[3 * PL + bn]);
    const ushort* src = &Vt[bn * CP];
#pragma unroll
    for (int c8 = 0; c8 < 4; c8++) {
        intx4 raw = *reinterpret_cast<const intx4*>(src + c8 * 8);
        const ushort* us = reinterpret_cast<const ushort*>(&raw);
#pragma unroll
        for (int e = 0; e < 8; e++) {
            tile[c8 * 8 + e][t] = bf16r(bf2f(us[e]) * f);
        }
    }
    __syncthreads();
#pragma unroll
    for (int c = 0; c < 32; c++) {
        Vp[((size_t)b * CP + c) * NN + nt * 256 + t] = tile[c][t];
    }
}

// ---------------- Kernel 4: pass B — out[c,i] = sum_j exp(S[j,i]) * v'[c,j]; fused back-proj + residual ----------------
// Block 256 = 4 waves: w&1 -> i-half (32 i each), w>>1 -> j-step parity. No layout-transform LDS:
// Q rows loaded with perm so the S-tile C-layout IS the B-operand layout of the second MFMA.
__global__ __launch_bounds__(256) void passB_kernel(
    const ushort* __restrict__ Qt, const ushort* __restrict__ Kt, const ushort* __restrict__ Vp,
    const float* __restrict__ x, const float* __restrict__ Wb, const float* __restrict__ bb,
    float* __restrict__ out) {
    __shared__ ushort qst[256 * CP];  // 16 KB : Q-chunk [256 j][32 o]
    __shared__ ushort vst[32 * 264];  // 16.5 KB : V'-chunk [32 c][256 j] (stride 264)

    int b = blockIdx.x >> 6, it = blockIdx.x & 63;
    int w = threadIdx.x >> 6, lane = threadIdx.x & 63;
    int l15 = lane & 15, q = lane >> 4;
    int iw = w & 1, jp = w >> 1;
    int i0 = it * 64 + iw * 32;

    short8 kf0 = load_frag(&Kt[((size_t)b * NN + i0 + l15) * CP + q * 8]);
    short8 kf1 = load_frag(&Kt[((size_t)b * NN + i0 + 16 + l15) * CP + q * 8]);

    floatx4 acc00 = (floatx4){0.f, 0.f, 0.f, 0.f};  // c 0-15  x i-half 0
    floatx4 acc10 = (floatx4){0.f, 0.f, 0.f, 0.f};  // c 16-31 x i-half 0
    floatx4 acc01 = (floatx4){0.f, 0.f, 0.f, 0.f};  // c 0-15  x i-half 1
    floatx4 acc11 = (floatx4){0.f, 0.f, 0.f, 0.f};  // c 16-31 x i-half 1

    // perm: A-row m holds Q[jl + 8*(m>>2) + (m&3)] (a0), +4 (a1) -> lane q's C-layout
    // output rows are exactly j = jl + 8q + {0..3} (s0) / {4..7} (s1) = B-frag k-positions.
    int qoff = (((l15 >> 2) * 8 + (l15 & 3)) * CP) + q * 8;
    int voff0 = l15 * 264 + q * 8;
    int voff1 = (16 + l15) * 264 + q * 8;

    for (int j0 = 0; j0 < NN; j0 += 256) {
        __syncthreads();
        {
            const intx4* qsrc = reinterpret_cast<const intx4*>(&Qt[((size_t)b * NN + j0) * CP]);
            intx4* qdst = reinterpret_cast<intx4*>(qst);
#pragma unroll
            for (int s = 0; s < 4; s++) qdst[threadIdx.x + 256 * s] = qsrc[threadIdx.x + 256 * s];
            int r = threadIdx.x >> 3, ci = threadIdx.x & 7;
            const intx4* vsrc = reinterpret_cast<const intx4*>(&Vp[((size_t)b * CP + r) * NN + j0]);
            intx4* vdst = reinterpret_cast<intx4*>(&vst[r * 264]);
#pragma unroll
            for (int s = 0; s < 4; s++) vdst[ci + 8 * s] = vsrc[ci + 8 * s];
        }
        __syncthreads();
#pragma unroll
        for (int jss = 0; jss < 4; jss++) {
            int jl = (jss * 2 + jp) * 32;
            short8 a0 = load_frag(&qst[jl * CP + qoff]);
            short8 a1 = load_frag(&qst[jl * CP + qoff + 4 * CP]);
            floatx4 z = (floatx4){0.f, 0.f, 0.f, 0.f};
            floatx4 s0A = __builtin_amdgcn_mfma_f32_16x16x32_bf16(a0, kf0, z, 0, 0, 0);
            floatx4 s1A = __builtin_amdgcn_mfma_f32_16x16x32_bf16(a1, kf0, z, 0, 0, 0);
            floatx4 s0B = __builtin_amdgcn_mfma_f32_16x16x32_bf16(a0, kf1, z, 0, 0, 0);
            floatx4 s1B = __builtin_amdgcn_mfma_f32_16x16x32_bf16(a1, kf1, z, 0, 0, 0);

            union { intx4 v; short8 s; } wa, wb2;
            wa.v.x = pk2(__expf(s0A[0]), __expf(s0A[1]));
            wa.v.y = pk2(__expf(s0A[2]), __expf(s0A[3]));
            wa.v.z = pk2(__expf(s1A[0]), __expf(s1A[1]));
            wa.v.w = pk2(__expf(s1A[2]), __expf(s1A[3]));
            wb2.v.x = pk2(__expf(s0B[0]), __expf(s0B[1]));
            wb2.v.y = pk2(__expf(s0B[2]), __expf(s0B[3]));
            wb2.v.z = pk2(__expf(s1B[0]), __expf(s1B[1]));
            wb2.v.w = pk2(__expf(s1B[2]), __expf(s1B[3]));

            short8 va0 = load_frag(&vst[voff0 + jl]);
            short8 va1 = load_frag(&vst[voff1 + jl]);
            acc00 = __builtin_amdgcn_mfma_f32_16x16x32_bf16(va0, wa.s, acc00, 0, 0, 0);
            acc10 = __builtin_amdgcn_mfma_f32_16x16x32_bf16(va1, wa.s, acc10, 0, 0, 0);
            acc01 = __builtin_amdgcn_mfma_f32_16x16x32_bf16(va0, wb2.s, acc01, 0, 0, 0);
            acc11 = __builtin_amdgcn_mfma_f32_16x16x32_bf16(va1, wb2.s, acc11, 0, 0, 0);
        }
    }

    // ---- merge jp partials + epilogue ----
    __syncthreads();
    float (*olds)[68] = reinterpret_cast<float(*)[68]>(qst);  // 8.7 KB alias over qst
    if (jp == 0) {
#pragma unroll
        for (int r = 0; r < 4; r++) {
            olds[q * 4 + r][iw * 32 + l15] = acc00[r];
            olds[16 + q * 4 + r][iw * 32 + l15] = acc10[r];
            olds[q * 4 + r][iw * 32 + 16 + l15] = acc01[r];
            olds[16 + q * 4 + r][iw * 32 + 16 + l15] = acc11[r];
        }
    }
    __syncthreads();
    if (jp == 1) {
#pragma unroll
        for (int r = 0; r < 4; r++) {
            olds[q * 4 + r][iw * 32 + l15] += acc00[r];
            olds[16 + q * 4 + r][iw * 32 + l15] += acc10[r];
            olds[q * 4 + r][iw * 32 + 16 + l15] += acc01[r];
            olds[16 + q * 4 + r][iw * 32 + 16 + l15] += acc11[r];
        }
    }
    __syncthreads();

    int t = threadIdx.x;
    int i4 = (t & 15) * 4;
    int cb = t >> 4;  // 0..15
    float4 accv[16];
#pragma unroll
    for (int cc = 0; cc < 16; cc++) {
        float bbv = bb[cb + 16 * cc];
        accv[cc].x = bbv; accv[cc].y = bbv; accv[cc].z = bbv; accv[cc].w = bbv;
    }
#pragma unroll 4
    for (int o = 0; o < 32; o++) {
        float4 ovv = *reinterpret_cast<const float4*>(&olds[o][i4]);
#pragma unroll
        for (int cc = 0; cc < 16; cc++) {
            float wv = Wb[(size_t)(cb + 16 * cc) * CP + o];
            accv[cc].x += wv * ovv.x;
            accv[cc].y += wv * ovv.y;
            accv[cc].z += wv * ovv.z;
            accv[cc].w += wv * ovv.w;
        }
    }
    size_t xbase = (size_t)b * CC * NN + (size_t)it * 64 + i4;
#pragma unroll
    for (int cc = 0; cc < 16; cc++) {
        int cout = cb + 16 * cc;
        float4 xv = *reinterpret_cast<const float4*>(&x[xbase + (size_t)cout * NN]);
        float4 res;
        res.x = accv[cc].x + xv.x;
        res.y = accv[cc].y + xv.y;
        res.z = accv[cc].z + xv.z;
        res.w = accv[cc].w + xv.w;
        *reinterpret_cast<float4*>(&out[xbase + (size_t)cout * NN]) = res;
    }
}

extern "C" void kernel_launch(void* const* d_in, const int* in_sizes, int n_in,
                              void* d_out, int out_size, void* d_ws, size_t ws_size,
                              hipStream_t stream) {
    const float* x  = (const float*)d_in[0];
    const float* Wq = (const float*)d_in[1];
    const float* bq = (const float*)d_in[2];
    const float* Wk = (const float*)d_in[3];
    const float* bk = (const float*)d_in[4];
    const float* Wv = (const float*)d_in[5];
    const float* bv = (const float*)d_in[6];
    const float* Wb = (const float*)d_in[7];
    const float* bb = (const float*)d_in[8];
    float* out = (float*)d_out;

    char* ws = (char*)d_ws;
    ushort* Qt  = (ushort*)(ws);                                  // 2 MB
    ushort* Kt  = (ushort*)(ws + (2u << 20));                     // 2 MB
    ushort* Vt  = (ushort*)(ws + (4u << 20));                     // 2 MB
    ushort* Vp  = (ushort*)(ws + (6u << 20));                     // 2 MB
    float*  Fp  = (float*) (ws + (8u << 20));                     // 512 KB (4 planes)
    ushort* W96 = (ushort*)(ws + (8u << 20) + (1u << 19));        // 48 KB

    prep_w<<<96, 256, 0, stream>>>(Wq, Wk, Wv, W96);
    proj_kernel<<<512, 256, 0, stream>>>(x, W96, bq, bk, bv, Qt, Kt, Vt);
    passA_kernel<<<2048, 256, 0, stream>>>(Qt, Kt, Fp);
    fold_kernel<<<128, 256, 0, stream>>>(Vt, Fp, Vp);
    passB_kernel<<<512, 256, 0, stream>>>(Qt, Kt, Vp, x, Wb, bb, out);
}

// Round 4
// 164.726 us; speedup vs baseline: 1.2822x; 1.2309x over previous
//
#include <hip/hip_runtime.h>
#include <hip/hip_bf16.h>

#define NB 8
#define CC 256
#define CP 32
#define NN 4096
#define LOG2E 1.44269504088896340736f

typedef __attribute__((ext_vector_type(8))) short short8;
typedef __attribute__((ext_vector_type(4))) float floatx4;
typedef __attribute__((ext_vector_type(4))) int intx4;

static __device__ __forceinline__ ushort bf16r(float f) {
    __hip_bfloat16 h = __float2bfloat16(f);
    return *reinterpret_cast<ushort*>(&h);
}
static __device__ __forceinline__ float bf2f(ushort u) {
    union { unsigned int i; float f; } x;
    x.i = ((unsigned int)u) << 16;
    return x.f;
}
static __device__ __forceinline__ short8 load_frag(const ushort* p) {
    intx4 v = *reinterpret_cast<const intx4*>(p);
    return *reinterpret_cast<short8*>(&v);
}
static __device__ __forceinline__ unsigned int pk2(float a, float b) {
    unsigned int ua = __float_as_uint(a) + 0x8000u;
    unsigned int ub = __float_as_uint(b) + 0x8000u;
    return (ua >> 16) | (ub & 0xFFFF0000u);
}
static __device__ __forceinline__ ushort pk1(float a) {
    return (ushort)((__float_as_uint(a) + 0x8000u) >> 16);
}
// 2^x via v_exp_f32 (inputs pre-scaled by log2e)
static __device__ __forceinline__ float fexp2(float x) {
#if defined(__has_builtin)
#if __has_builtin(__builtin_amdgcn_exp2f)
    return __builtin_amdgcn_exp2f(x);
#else
    return __expf(x * 0.69314718055994530942f);
#endif
#else
    return __expf(x * 0.69314718055994530942f);
#endif
}

// ---------------- Kernel 0: W prep. blocks 0..95: Wq/Wk/Wv -> W96 bf16 (Wq scaled by log2e).
// blocks 96..127: Wb -> W2b bf16 [256][32] flat. ----------------
__global__ void prep_w(const float* __restrict__ Wq, const float* __restrict__ Wk,
                       const float* __restrict__ Wv, const float* __restrict__ Wb,
                       ushort* __restrict__ W96, ushort* __restrict__ W2b) {
    int r = blockIdx.x, c = threadIdx.x;
    if (r < 96) {
        const float* src = (r < 32) ? (Wq + r * CC) : ((r < 64) ? (Wk + (r - 32) * CC) : (Wv + (r - 64) * CC));
        float scale = (r < 32) ? LOG2E : 1.0f;
        W96[r * CC + c] = bf16r(src[c] * scale);
    } else {
        int idx = (r - 96) * 256 + c;
        W2b[idx] = bf16r(Wb[idx]);
    }
}

// ---------------- Kernel 1: projection x -> Qt, Kt, Vt (all [b][n][32] bf16; Q pre-scaled by log2e) ----------------
__global__ __launch_bounds__(256) void proj_kernel(
    const float* __restrict__ x, const ushort* __restrict__ W96,
    const float* __restrict__ bq, const float* __restrict__ bk, const float* __restrict__ bv,
    ushort* __restrict__ Qt, ushort* __restrict__ Kt, ushort* __restrict__ Vt) {
    __shared__ ushort xt[64 * 264];  // [n_local][c], stride 264
    int b = blockIdx.x >> 6, nt = blockIdx.x & 63;
    int t = threadIdx.x;
    int n0 = nt * 64;
    {
        // thread t: c-quad cq = t>>4, n4 = (t&15)*4 ; loops cc over 4 c-blocks of 64
        int cq = t >> 4, n4 = (t & 15) * 4;
#pragma unroll
        for (int cc = 0; cc < 4; cc++) {
            int c_base = cc * 64 + cq * 4;
            float4 xv[4];
#pragma unroll
            for (int e = 0; e < 4; e++)
                xv[e] = *reinterpret_cast<const float4*>(&x[((size_t)b * CC + c_base + e) * NN + n0 + n4]);
            const float* xs = reinterpret_cast<const float*>(xv);
#pragma unroll
            for (int jj = 0; jj < 4; jj++) {
                ushort4 u;
                u.x = pk1(xs[0 * 4 + jj]);
                u.y = pk1(xs[1 * 4 + jj]);
                u.z = pk1(xs[2 * 4 + jj]);
                u.w = pk1(xs[3 * 4 + jj]);
                *reinterpret_cast<ushort4*>(&xt[(n4 + jj) * 264 + c_base]) = u;
            }
        }
    }
    __syncthreads();
    int w = t >> 6, lane = t & 63, l15 = lane & 15, q = lane >> 4;
    floatx4 acc[6];
#pragma unroll
    for (int k = 0; k < 6; k++) acc[k] = (floatx4){0.f, 0.f, 0.f, 0.f};
#pragma unroll
    for (int ks = 0; ks < 8; ks++) {
        short8 bfrag = load_frag(&xt[(w * 16 + l15) * 264 + ks * 32 + q * 8]);
#pragma unroll
        for (int ot = 0; ot < 6; ot++) {
            short8 afrag = load_frag(&W96[(size_t)(ot * 16 + l15) * CC + ks * 32 + q * 8]);
            acc[ot] = __builtin_amdgcn_mfma_f32_16x16x32_bf16(afrag, bfrag, acc[ot], 0, 0, 0);
        }
    }
    int n = n0 + w * 16 + l15;
#pragma unroll
    for (int ot = 0; ot < 6; ot++) {
        const float* bias = (ot < 2) ? bq : ((ot < 4) ? bk : bv);
        ushort* dst = (ot < 2) ? Qt : ((ot < 4) ? Kt : Vt);
        int o0 = (ot & 1) * 16 + q * 4;
        float4 b4 = *reinterpret_cast<const float4*>(bias + o0);
        float sc = (ot < 2) ? LOG2E : 1.0f;
        ushort4 pk;
        pk.x = bf16r(acc[ot][0] + b4.x * sc);
        pk.y = bf16r(acc[ot][1] + b4.y * sc);
        pk.z = bf16r(acc[ot][2] + b4.z * sc);
        pk.w = bf16r(acc[ot][3] + b4.w * sc);
        *reinterpret_cast<ushort4*>(&dst[((size_t)b * NN + n) * CP + o0]) = pk;
    }
}

// ---------------- Kernel 2: pass A — partial row sums of 2^(S') over m-quarters ----------------
__global__ __launch_bounds__(256, 4) void passA_kernel(
    const ushort* __restrict__ Qt, const ushort* __restrict__ Kt, float* __restrict__ Fp) {
    __shared__ ushort kst[256 * 40];  // 20 KB, padded rows
    int bid = blockIdx.x;
    int mq = bid & 3, jt = (bid >> 2) & 63, b = bid >> 8;
    int w = threadIdx.x >> 6, lane = threadIdx.x & 63;
    int l15 = lane & 15, q = lane >> 4;
    int j = jt * 64 + w * 16 + l15;

    short8 af = load_frag(&Qt[((size_t)b * NN + j) * CP + q * 8]);
    floatx4 lacc = (floatx4){0.f, 0.f, 0.f, 0.f};

    for (int mc = 0; mc < 4; mc++) {
        int m0 = mq * 1024 + mc * 256;
        __syncthreads();
        {
            const intx4* src = reinterpret_cast<const intx4*>(&Kt[((size_t)b * NN + m0) * CP]);
            intx4* dst = reinterpret_cast<intx4*>(kst);
#pragma unroll
            for (int s = 0; s < 4; s++) {
                int g = threadIdx.x + 256 * s;
                dst[(g >> 2) * 5 + (g & 3)] = src[g];
            }
        }
        __syncthreads();
#pragma unroll
        for (int ms = 0; ms < 16; ms++) {
            short8 bf = load_frag(&kst[(ms * 16 + l15) * 40 + q * 8]);
            floatx4 z = (floatx4){0.f, 0.f, 0.f, 0.f};
            floatx4 s = __builtin_amdgcn_mfma_f32_16x16x32_bf16(af, bf, z, 0, 0, 0);
            lacc[0] += fexp2(s[0]);
            lacc[1] += fexp2(s[1]);
            lacc[2] += fexp2(s[2]);
            lacc[3] += fexp2(s[3]);
        }
    }
#pragma unroll
    for (int d = 1; d < 16; d <<= 1) {
        lacc[0] += __shfl_xor(lacc[0], d, 64);
        lacc[1] += __shfl_xor(lacc[1], d, 64);
        lacc[2] += __shfl_xor(lacc[2], d, 64);
        lacc[3] += __shfl_xor(lacc[3], d, 64);
    }
    if (l15 == 0) {
        float4 f4;
        f4.x = lacc[0]; f4.y = lacc[1]; f4.z = lacc[2]; f4.w = lacc[3];
        *reinterpret_cast<float4*>(&Fp[((size_t)mq * NB + b) * NN + jt * 64 + w * 16 + q * 4]) = f4;
    }
}

// ---------------- Kernel 3: combine Fp, fold into V, transpose -> Vp[b][32][n] bf16 ----------------
__global__ __launch_bounds__(256) void fold_kernel(
    const ushort* __restrict__ Vt, const float* __restrict__ Fp, ushort* __restrict__ Vp) {
    __shared__ ushort tile[32 * 136];
    const size_t PL = (size_t)NB * NN;
    int b = blockIdx.x >> 5, nc = blockIdx.x & 31;
    int t = threadIdx.x;
    int half = t >> 7, nl = t & 127;
    int n = nc * 128 + nl;
    size_t bn = (size_t)b * NN + n;
    float f = 1.0f / (Fp[bn] + Fp[PL + bn] + Fp[2 * PL + bn] + Fp[3 * PL + bn]);
    const ushort* src = &Vt[bn * CP + half * 16];
#pragma unroll
    for (int g = 0; g < 2; g++) {
        intx4 raw = *reinterpret_cast<const intx4*>(src + g * 8);
        const ushort* us = reinterpret_cast<const ushort*>(&raw);
#pragma unroll
        for (int e = 0; e < 8; e++) {
            tile[(half * 16 + g * 8 + e) * 136 + nl] = pk1(bf2f(us[e]) * f);
        }
    }
    __syncthreads();
#pragma unroll
    for (int cc = 0; cc < 16; cc++) {
        int c = half * 16 + cc;
        Vp[((size_t)b * CP + c) * NN + nc * 128 + nl] = tile[c * 136 + nl];
    }
}

// ---------------- Kernel 4: pass B — O[32c][32i] over all j, fused MFMA back-proj + bias + residual ----------------
// grid 1024 = b(8) x it(128, 32-i tiles). 4 waves split j 4-way; partials merged in LDS.
__global__ __launch_bounds__(256, 4) void passB_kernel(
    const ushort* __restrict__ Qt, const ushort* __restrict__ Kt, const ushort* __restrict__ Vp,
    const ushort* __restrict__ W2b, const float* __restrict__ bb, const float* __restrict__ x,
    float* __restrict__ out) {
    __shared__ ushort qst[256 * 40];  // 20 KB, padded (aliased as olds4 in epilogue)
    __shared__ ushort vst[32 * 264];  // 16.5 KB

    int bid = blockIdx.x;
    int it = bid & 127, b = bid >> 7;
    int w = threadIdx.x >> 6, lane = threadIdx.x & 63;
    int l15 = lane & 15, q = lane >> 4;
    int jp = w;
    int i0 = it * 32;

    short8 kf0 = load_frag(&Kt[((size_t)b * NN + i0 + l15) * CP + q * 8]);
    short8 kf1 = load_frag(&Kt[((size_t)b * NN + i0 + 16 + l15) * CP + q * 8]);

    floatx4 acc00 = (floatx4){0.f, 0.f, 0.f, 0.f};  // c 0-15  x i 0-15
    floatx4 acc10 = (floatx4){0.f, 0.f, 0.f, 0.f};  // c 16-31 x i 0-15
    floatx4 acc01 = (floatx4){0.f, 0.f, 0.f, 0.f};  // c 0-15  x i 16-31
    floatx4 acc11 = (floatx4){0.f, 0.f, 0.f, 0.f};  // c 16-31 x i 16-31

    int qrow = (l15 >> 2) * 8 + (l15 & 3);  // perm: C-layout of S == B-frag layout of PV

    for (int jc = 0; jc < 16; jc++) {
        int j0 = jc * 256;
        __syncthreads();
        {
            const intx4* qsrc = reinterpret_cast<const intx4*>(&Qt[((size_t)b * NN + j0) * CP]);
            intx4* qdst = reinterpret_cast<intx4*>(qst);
#pragma unroll
            for (int s = 0; s < 4; s++) {
                int g = threadIdx.x + 256 * s;
                qdst[(g >> 2) * 5 + (g & 3)] = qsrc[g];
            }
            int r = threadIdx.x >> 3, ci = threadIdx.x & 7;
            const intx4* vsrc = reinterpret_cast<const intx4*>(&Vp[((size_t)b * CP + r) * NN + j0]);
            intx4* vdst = reinterpret_cast<intx4*>(&vst[r * 264]);
#pragma unroll
            for (int s = 0; s < 4; s++) vdst[ci + 8 * s] = vsrc[ci + 8 * s];
        }
        __syncthreads();
#pragma unroll
        for (int ss = 0; ss < 2; ss++) {
            int jl = (ss * 4 + jp) * 32;
            short8 va0 = load_frag(&vst[l15 * 264 + jl + q * 8]);
            short8 va1 = load_frag(&vst[(16 + l15) * 264 + jl + q * 8]);
            short8 a0 = load_frag(&qst[(jl + qrow) * 40 + q * 8]);
            short8 a1 = load_frag(&qst[(jl + qrow + 4) * 40 + q * 8]);
            floatx4 z = (floatx4){0.f, 0.f, 0.f, 0.f};
            floatx4 s0A = __builtin_amdgcn_mfma_f32_16x16x32_bf16(a0, kf0, z, 0, 0, 0);
            floatx4 s1A = __builtin_amdgcn_mfma_f32_16x16x32_bf16(a1, kf0, z, 0, 0, 0);
            floatx4 s0B = __builtin_amdgcn_mfma_f32_16x16x32_bf16(a0, kf1, z, 0, 0, 0);
            floatx4 s1B = __builtin_amdgcn_mfma_f32_16x16x32_bf16(a1, kf1, z, 0, 0, 0);

            union { intx4 v; short8 s; } wa, wb2;
            wa.v.x = pk2(fexp2(s0A[0]), fexp2(s0A[1]));
            wa.v.y = pk2(fexp2(s0A[2]), fexp2(s0A[3]));
            wa.v.z = pk2(fexp2(s1A[0]), fexp2(s1A[1]));
            wa.v.w = pk2(fexp2(s1A[2]), fexp2(s1A[3]));
            wb2.v.x = pk2(fexp2(s0B[0]), fexp2(s0B[1]));
            wb2.v.y = pk2(fexp2(s0B[2]), fexp2(s0B[3]));
            wb2.v.z = pk2(fexp2(s1B[0]), fexp2(s1B[1]));
            wb2.v.w = pk2(fexp2(s1B[2]), fexp2(s1B[3]));

            acc00 = __builtin_amdgcn_mfma_f32_16x16x32_bf16(va0, wa.s, acc00, 0, 0, 0);
            acc10 = __builtin_amdgcn_mfma_f32_16x16x32_bf16(va1, wa.s, acc10, 0, 0, 0);
            acc01 = __builtin_amdgcn_mfma_f32_16x16x32_bf16(va0, wb2.s, acc01, 0, 0, 0);
            acc11 = __builtin_amdgcn_mfma_f32_16x16x32_bf16(va1, wb2.s, acc11, 0, 0, 0);
        }
    }

    // ---- merge 4 jp partials via LDS (alias over qst): olds4[jp][32 c][33] ----
    __syncthreads();
    float* olds4 = reinterpret_cast<float*>(qst);
    int mbase = jp * (32 * 33);
#pragma unroll
    for (int r = 0; r < 4; r++) {
        olds4[mbase + (q * 4 + r) * 33 + l15] = acc00[r];
        olds4[mbase + (16 + q * 4 + r) * 33 + l15] = acc10[r];
        olds4[mbase + (q * 4 + r) * 33 + 16 + l15] = acc01[r];
        olds4[mbase + (16 + q * 4 + r) * 33 + 16 + l15] = acc11[r];
    }
    __syncthreads();

    // ---- epilogue: back[c,i] = Wb.O + bb + x ; wave w handles c in [w*64, w*64+64) ----
    short8 bfr[2];
#pragma unroll
    for (int s = 0; s < 2; s++) {
        float o8[8];
#pragma unroll
        for (int jj = 0; jj < 8; jj++) {
            int o = q * 8 + jj;
            int idx = o * 33 + s * 16 + l15;
            o8[jj] = olds4[idx] + olds4[1056 + idx] + olds4[2112 + idx] + olds4[3168 + idx];
        }
        union { intx4 v; short8 sh; } u;
        u.v.x = pk2(o8[0], o8[1]);
        u.v.y = pk2(o8[2], o8[3]);
        u.v.z = pk2(o8[4], o8[5]);
        u.v.w = pk2(o8[6], o8[7]);
        bfr[s] = u.sh;
    }
    int c0 = w * 64;
#pragma unroll
    for (int cs = 0; cs < 4; cs++) {
        short8 af = load_frag(&W2b[(size_t)(c0 + cs * 16 + l15) * CP + q * 8]);
#pragma unroll
        for (int s = 0; s < 2; s++) {
            floatx4 z = (floatx4){0.f, 0.f, 0.f, 0.f};
            floatx4 d = __builtin_amdgcn_mfma_f32_16x16x32_bf16(af, bfr[s], z, 0, 0, 0);
#pragma unroll
            for (int r = 0; r < 4; r++) {
                int c = c0 + cs * 16 + q * 4 + r;
                int i = i0 + s * 16 + l15;
                size_t idx = ((size_t)b * CC + c) * NN + i;
                out[idx] = d[r] + bb[c] + x[idx];
            }
        }
    }
}

extern "C" void kernel_launch(void* const* d_in, const int* in_sizes, int n_in,
                              void* d_out, int out_size, void* d_ws, size_t ws_size,
                              hipStream_t stream) {
    const float* x  = (const float*)d_in[0];
    const float* Wq = (const float*)d_in[1];
    const float* bq = (const float*)d_in[2];
    const float* Wk = (const float*)d_in[3];
    const float* bk = (const float*)d_in[4];
    const float* Wv = (const float*)d_in[5];
    const float* bv = (const float*)d_in[6];
    const float* Wb = (const float*)d_in[7];
    const float* bb = (const float*)d_in[8];
    float* out = (float*)d_out;

    char* ws = (char*)d_ws;
    ushort* Qt  = (ushort*)(ws);                                   // 0..2MB
    ushort* Kt  = (ushort*)(ws + (2u << 20));                      // 2..4MB
    ushort* Vp  = (ushort*)(ws + (4u << 20));                      // 4..6MB
    ushort* Vt  = (ushort*)(ws + (6u << 20));                      // 6..8MB
    float*  Fp  = (float*) (ws + (8u << 20));                      // 8..8.5MB
    ushort* W96 = (ushort*)(ws + (8u << 20) + (1u << 19));         // 48KB
    ushort* W2b = (ushort*)(ws + (8u << 20) + (1u << 19) + (48u << 10));  // 16KB

    prep_w<<<128, 256, 0, stream>>>(Wq, Wk, Wv, Wb, W96, W2b);
    proj_kernel<<<512, 256, 0, stream>>>(x, W96, bq, bk, bv, Qt, Kt, Vt);
    passA_kernel<<<2048, 256, 0, stream>>>(Qt, Kt, Fp);
    fold_kernel<<<256, 256, 0, stream>>>(Vt, Fp, Vp);
    passB_kernel<<<1024, 256, 0, stream>>>(Qt, Kt, Vp, W2b, bb, x, out);
}